// Round 15
// baseline (243.800 us; speedup 1.0000x reference)
//
#include <hip/hip_runtime.h>
#include <math.h>

#define NN 100000
#define NE 1600000
#define NT (NE + NN)   // 1700000 edges incl. self-loops
#define DD 128
#define NB 500          // dst buckets
#define BR 200          // node range per bucket (NB*BR == NN)
#define BCAP 4096       // bucket capacity (mean 3200, sigma 56 -> 15.9 sigma headroom)
#define NCH 2048        // edges per bucket-sort block
#define NBK 782         // ceil(NE/NCH)
#define NBG 1563        // ceil(NN/64) gemm blocks
#define PW 68           // padded LDS row stride in uints (64 + 4 -> 2-way banks only)
#define BMAGIC 21474837u // ceil(2^32/200); exact for d < 100000

typedef unsigned int uint;
typedef unsigned short ushort;
typedef __attribute__((ext_vector_type(8))) short bf16x8;
typedef __attribute__((ext_vector_type(4))) float f32x4;

// round-to-nearest-even fp32 -> bf16 (16-bit payload in a uint)
__device__ __forceinline__ uint bfr(float f){
  uint u = __float_as_uint(f);
  return (u + 0x7FFFu + ((u >> 16) & 1u)) >> 16;
}
__device__ __forceinline__ uint pk2(float a, float b){
  return (bfr(a) & 0xFFFFu) | (bfr(b) << 16);
}
__device__ __forceinline__ bf16x8 asbf(uint4 u){
  union { uint4 u; bf16x8 b; } c; c.u = u; return c.b;
}

// ---------------- K1: weight transposes (blocks 0,1) + gcnt zero (block 2) ----------------
__global__ __launch_bounds__(256) void k_init(const float* __restrict__ W1f, const float* __restrict__ W2f,
    uint* __restrict__ Wt1, uint* __restrict__ Wt2, int* __restrict__ gcnt){
  int t = threadIdx.x;
  if (blockIdx.x == 2){
    for (int i = t; i < 8000; i += 256) gcnt[i] = 0;
    return;
  }
  const float* W = blockIdx.x ? W2f : W1f;
  uint* Wt = blockIdx.x ? Wt2 : Wt1;
  int n = t >> 1, k0 = (t & 1) * 64;
  for (int kk = 0; kk < 64; kk += 2){
    float v0 = W[(size_t)(k0+kk  )*DD + n];
    float v1 = W[(size_t)(k0+kk+1)*DD + n];
    Wt[(size_t)n*64 + ((k0+kk)>>1)] = pk2(v0, v1);
  }
}

// ---------------- shared GEMM body: Y[r] = bf16((X@W)[r])  (UNSCALED) ----------------
// 64 rows/block. Staging coalesced into padded LDS (2-way banks only);
// fragments via ds_read_b128; lane (g,li): Wt row nt*16+li, X row wv*16+li,
// k-chunk ks*32+g*8. C/D: lane owns row r, cols nt*16+g*4+reg (HW-verified).
template<int IN_BF16>
__device__ __forceinline__ void gemm_body(uint* __restrict__ Ws, uint* __restrict__ Xs,
    const void* __restrict__ Xv, const uint* __restrict__ Wt,
    uint* __restrict__ Y, int row0){
  int t = threadIdx.x;
  // stage Wt: 2048 uint4, coalesced
  #pragma unroll
  for (int it = 0; it < 8; ++it){
    int f = it*256 + t;
    uint4 v = ((const uint4*)Wt)[f];
    int row = f >> 4, c4 = f & 15;
    *(uint4*)&Ws[row*PW + c4*4] = v;
  }
  // stage X tile (64 rows), coalesced; zero-fill invalid rows
  if (!IN_BF16){
    const float* X = (const float*)Xv;
    #pragma unroll
    for (int it = 0; it < 8; ++it){
      int f = it*256 + t;                  // 0..2047 float4
      int row = f >> 5, c4 = f & 31;
      int gr = row0 + row;
      float4 v = (gr < NN) ? ((const float4*)X)[(size_t)gr*32 + c4]
                           : make_float4(0.f,0.f,0.f,0.f);
      uint2 p; p.x = pk2(v.x, v.y); p.y = pk2(v.z, v.w);
      *(uint2*)&Xs[row*PW + c4*2] = p;
    }
  } else {
    const uint* X = (const uint*)Xv;
    #pragma unroll
    for (int it = 0; it < 4; ++it){
      int f = it*256 + t;                  // 0..1023 uint4
      int row = f >> 4, c4 = f & 15;
      int gr = row0 + row;
      uint4 v = (gr < NN) ? ((const uint4*)X)[(size_t)gr*16 + c4]
                          : make_uint4(0,0,0,0);
      *(uint4*)&Xs[row*PW + c4*4] = v;
    }
  }
  __syncthreads();

  int wv = t >> 6, l = t & 63;
  int g = l >> 4, li = l & 15;
  int rb = wv*16 + li;                    // row within block
  int r  = row0 + rb;
  f32x4 acc[8];
  #pragma unroll
  for (int i = 0; i < 8; ++i) acc[i] = (f32x4){0.f,0.f,0.f,0.f};

  #pragma unroll
  for (int ks = 0; ks < 4; ++ks){
    int c = (ks*4 + g)*4;                 // uint offset of this lane's k-chunk
    bf16x8 bfrag = asbf(*(const uint4*)&Xs[rb*PW + c]);
    #pragma unroll
    for (int nt = 0; nt < 8; ++nt){
      bf16x8 afrag = asbf(*(const uint4*)&Ws[(nt*16 + li)*PW + c]);
      acc[nt] = __builtin_amdgcn_mfma_f32_16x16x32_bf16(afrag, bfrag, acc[nt], 0, 0, 0);
    }
  }
  if (r < NN){
    #pragma unroll
    for (int nt = 0; nt < 8; ++nt){
      uint2 o;
      o.x = pk2(acc[nt][0], acc[nt][1]);
      o.y = pk2(acc[nt][2], acc[nt][3]);
      *(uint2*)&Y[(size_t)r*64 + nt*8 + g*2] = o;   // row-major packed
    }
  }
}

// ---------------- K2: fused [bucket sort (blocks 0..781) | layer-1 GEMM (782..2344)] ----------------
// Independent halves after k_init: bucket = LDS/atomic/stream bound, gemm1 = MFMA/HBM.
// gemm1 no longer needs dis (H unscaled) -> overlaps the whole count chain.
__global__ __launch_bounds__(256, 3) void k_A(const int* __restrict__ ei,
    int* __restrict__ gcnt, uint* __restrict__ bedge,
    const float* __restrict__ X, const uint* __restrict__ Wt1, uint* __restrict__ H){
  __shared__ uint smem[192*PW];           // gemm Ws|Xs ; bucket ent|bbs|hist|fl|gb
  int t = threadIdx.x;
  if (blockIdx.x >= NBK){
    gemm_body<0>(smem, smem + 128*PW, X, Wt1, H, (blockIdx.x - NBK)*64);
    return;
  }
  uint*   ent  = smem;                    // 2048 uints
  ushort* bbs  = (ushort*)(smem + NCH);   // 2048 ushorts (1024 uints)
  int*    hist = (int*)(smem + NCH + NCH/2);
  int*    fl   = hist + NB;
  int*    gb   = fl + NB;                 // end: 3072+1500 = 4572 uints < 13056
  int base = blockIdx.x * NCH;
  int nv = NE - base; if (nv > NCH) nv = NCH;
  for (int b = t; b < NB; b += 256){ hist[b] = 0; fl[b] = 0; }
  __syncthreads();
  for (int j = t; j < nv; j += 256){
    int i = base + j;                      // coalesced
    uint s = (uint)ei[i];
    uint d = (uint)ei[NE + i];
    uint b = __umulhi(d, BMAGIC);          // d / 200
    uint dl = d - b*BR;
    ent[j] = s | (dl << 17);
    bbs[j] = (ushort)b;
    atomicAdd(&hist[b], 1);
  }
  __syncthreads();
  for (int b = t; b < NB; b += 256){
    int h = hist[b];
    gb[b] = h ? atomicAdd(&gcnt[b*16], h) : 0;   // bulk reservation
  }
  __syncthreads();
  for (int j = t; j < nv; j += 256){
    uint b = bbs[j];
    int q = atomicAdd(&fl[b], 1);          // LDS fill
    bedge[(size_t)b*BCAP + gb[b] + q] = ent[j];
  }
}

// ---------------- K3: fused [bucket-total exclusive scan (block 0) | degree -> deg,dis (500)] ----------------
__global__ __launch_bounds__(256) void k_B(const int* __restrict__ gcnt, int* __restrict__ bbase,
    const uint* __restrict__ bedge, int* __restrict__ deg, float* __restrict__ dis){
  __shared__ int sm[256];
  int t = threadIdx.x;
  if (blockIdx.x == 0){
    int i0 = 2*t, i1 = 2*t + 1;
    int v0 = (i0 < NB) ? (gcnt[i0*16] + BR) : 0;
    int v1 = (i1 < NB) ? (gcnt[i1*16] + BR) : 0;
    int p = v0 + v1;
    sm[t] = p;
    __syncthreads();
    for (int off = 1; off < 256; off <<= 1){
      int a = (t >= off) ? sm[t-off] : 0;
      __syncthreads();
      sm[t] += a;
      __syncthreads();
    }
    int excl = sm[t] - p;
    if (i0 < NB) bbase[i0] = excl;
    if (i1 < NB) bbase[i1] = excl + v0;
    return;
  }
  int b = blockIdx.x - 1;
  int* cl = sm;                            // BR <= 256
  if (t < BR) cl[t] = 0;
  __syncthreads();
  int cnt = gcnt[b*16];
  for (int e = t; e < cnt; e += 256){
    atomicAdd(&cl[bedge[(size_t)b*BCAP + e] >> 17], 1);
  }
  __syncthreads();
  if (t < BR){
    int n = b*BR + t;
    int dg = cl[t];
    deg[n] = dg;                           // in-degree excl self-loop
    dis[n] = rsqrtf((float)(dg + 1));
  }
}

// ---------------- K4: CSR build; es = src(17b) | bf16(dis[src]) sans sign (15b) <<17 ----------------
// dis[src] gathers hit L2 (400KB table). rowptr globally monotone.
__global__ __launch_bounds__(256) void k_C(const int* __restrict__ gcnt,
    const int* __restrict__ bbase, const uint* __restrict__ bedge,
    const int* __restrict__ deg, const float* __restrict__ dis,
    int* __restrict__ rowptr, uint* __restrict__ es){
  __shared__ int cl[BR];
  __shared__ int fl[BR];
  __shared__ int pf[256];
  int b = blockIdx.x, t = threadIdx.x;
  int base = bbase[b];
  if (t < BR){ cl[t] = deg[b*BR + t]; fl[t] = 0; }
  __syncthreads();
  // inclusive scan over (cl[i]+1)
  int v = (t < BR) ? (cl[t] + 1) : 0;
  pf[t] = v;
  __syncthreads();
  for (int off = 1; off < 256; off <<= 1){
    int a = (t >= off) ? pf[t-off] : 0;
    __syncthreads();
    pf[t] += a;
    __syncthreads();
  }
  if (t < BR){
    int n  = b*BR + t;
    int p0 = base + pf[t] - v;             // exclusive prefix (globally monotone)
    rowptr[n] = p0;
    es[p0 + cl[t]] = (uint)n | ((bfr(dis[n]) & 0x7FFFu) << 17);  // self-loop last
  }
  if (b == NB-1 && t == 0) rowptr[NN] = NT;
  __syncthreads();
  int cnt = gcnt[b*16];
  for (int e = t; e < cnt; e += 256){
    uint u = bedge[(size_t)b*BCAP + e];
    uint s = u & 0x1FFFFu;
    int  dloc = u >> 17;
    int  q  = atomicAdd(&fl[dloc], 1);
    int  p0 = base + pf[dloc] - (cl[dloc] + 1);
    es[p0 + q] = s | ((bfr(dis[s]) & 0x7FFFu) << 17);
  }
}

// ---------------- layer-2 GEMM (bf16 input, unscaled out) ----------------
__global__ __launch_bounds__(256, 3) void k_gemm2(const uint* __restrict__ X,
    const uint* __restrict__ Wt, uint* __restrict__ Y){
  __shared__ uint smem[192*PW];
  gemm_body<1>(smem, smem + 128*PW, X, Wt, Y, blockIdx.x*64);
}

// ---------------- CSR aggregation + bias + ELU ----------------
// out[n] = elu(dis[n] * sum_{s} w_s * h[s] + b), w_s = bf16(dis[s]) from es.
// one WAVE per node (4 nodes / 256-thread block); lane = bf16 channel pair;
// 16x edge unroll -> 16 gathers in flight per wave.
template<int OUT_BF16>
__global__ __launch_bounds__(256) void k_agg(const uint* __restrict__ H,
    const int* __restrict__ rowptr, const float* __restrict__ dis,
    const uint* __restrict__ es, const float* __restrict__ bias,
    void* __restrict__ outv){
  int wid  = threadIdx.x >> 6;
  int lane = threadIdx.x & 63;
  int n = blockIdx.x*4 + wid;            // grid*4 == NN exactly
  int e0 = rowptr[n];
  int e1 = rowptr[n+1];
  float a0 = 0.f, a1 = 0.f, a2 = 0.f, a3 = 0.f;
  int e = e0;

#define ASTEP(k,A,B) { uint p##k = es[e+k]; \
    uint h##k = H[(size_t)(p##k & 0x1FFFFu)*64 + lane]; \
    float w##k = __uint_as_float((p##k >> 17) << 16); \
    A = fmaf(w##k, __uint_as_float(h##k << 16), A); \
    B = fmaf(w##k, __uint_as_float(h##k & 0xFFFF0000u), B); }

  for (; e + 16 <= e1; e += 16){
    ASTEP( 0,a0,a1) ASTEP( 1,a2,a3) ASTEP( 2,a0,a1) ASTEP( 3,a2,a3)
    ASTEP( 4,a0,a1) ASTEP( 5,a2,a3) ASTEP( 6,a0,a1) ASTEP( 7,a2,a3)
    ASTEP( 8,a0,a1) ASTEP( 9,a2,a3) ASTEP(10,a0,a1) ASTEP(11,a2,a3)
    ASTEP(12,a0,a1) ASTEP(13,a2,a3) ASTEP(14,a0,a1) ASTEP(15,a2,a3)
  }
  for (; e + 4 <= e1; e += 4){
    ASTEP(0,a0,a1) ASTEP(1,a2,a3) ASTEP(2,a0,a1) ASTEP(3,a2,a3)
  }
  for (; e < e1; ++e){
    ASTEP(0,a0,a1)
  }
#undef ASTEP

  float dn = dis[n];
  float2 b = *(const float2*)&bias[lane*2];
  float v0 = fmaf(dn, a0 + a2, b.x);
  float v1 = fmaf(dn, a1 + a3, b.y);
  v0 = (v0 > 0.f) ? v0 : expm1f(v0);
  v1 = (v1 > 0.f) ? v1 : expm1f(v1);
  if (OUT_BF16){
    ((uint*)outv)[(size_t)n*64 + lane] = pk2(v0, v1);
  } else {
    float2 o; o.x = v0; o.y = v1;
    *(float2*)&((float*)outv)[(size_t)n*DD + lane*2] = o;
  }
}

// ---------------- launch ----------------

extern "C" void kernel_launch(void* const* d_in, const int* in_sizes, int n_in,
                              void* d_out, int out_size, void* d_ws, size_t ws_size,
                              hipStream_t stream){
  const float* x  = (const float*)d_in[0];
  const int*   ei = (const int*)d_in[1];   // [2, NE]: src row then dst row
  const float* W1 = (const float*)d_in[2];
  const float* b1 = (const float*)d_in[3];
  const float* W2 = (const float*)d_in[4];
  const float* b2 = (const float*)d_in[5];

  // workspace carve-up (int units), every region 64-int (256B) aligned.
  // H alignment CRITICAL (misaligned 256B rows -> +42% gather FETCH, R4..R8).
  // out1 = FULL 6.4M uints (R11 lesson); aliases bedge (dead after k_C) --
  // safe: agg<1> (only out1 writer) runs after k_C. H2 = H (dead after agg<1>).
  int*   ws_i   = (int*)d_ws;
  int*   gcnt   = ws_i + 0;                 // [0, 8000)  500*16 padded counters
  int*   bbase  = ws_i + 8000;              // [8000, 8576)
  float* dis    = (float*)(ws_i + 8576);    // [8576, 108608)
  int*   rowptr = ws_i + 108608;            // [108608, 208704)  100001 used
  int*   deg    = ws_i + 208704;            // [208704, 308736)
  uint*  Wt1    = (uint*)(ws_i + 308736);   // [308736, 316928)  128x128 bf16
  uint*  Wt2    = (uint*)(ws_i + 316928);   // [316928, 325120)
  uint*  es     = (uint*)(ws_i + 325120);   // [325120, 2025152)  1700000 used
  uint*  bedge  = (uint*)(ws_i + 2025152);  // [2025152, 4073152)  dead after k_C
  uint*  out1   = (uint*)(ws_i + 2025152);  // [2025152, 8425152)  6.4M uints, %256==0
  uint*  H      = (uint*)(ws_i + 8425152);  // [8425152, 14825152) 6.4M uints, %256==0
  uint*  H2     = H;                        //   reused: H dead after agg<1>
  // total 14825152 ints = 59.3 MB (proven fits, R14)

  // K1: Wt transposes + gcnt zero
  k_init<<<3, 256, 0, stream>>>(W1, W2, Wt1, Wt2, gcnt);
  // K2: [bucket sort | layer-1 GEMM: H = bf16(x@W1), unscaled]
  k_A   <<<NBK + NBG, 256, 0, stream>>>(ei, gcnt, bedge, x, Wt1, H);
  // K3: [bucket-total scan | degree -> deg, dis]
  k_B   <<<NB + 1, 256, 0, stream>>>(gcnt, bbase, bedge, deg, dis);
  // K4: CSR build, es packs bf16(dis[src])
  k_C   <<<NB, 256, 0, stream>>>(gcnt, bbase, bedge, deg, dis, rowptr, es);
  // layer-1 agg: out1 = bf16(elu(dis*agg + b1))
  k_agg<1><<<25000, 256, 0, stream>>>(H, rowptr, dis, es, b1, out1);
  // layer-2 GEMM: H2 = bf16(out1@W2), unscaled
  k_gemm2 <<<NBG, 256, 0, stream>>>(out1, Wt2, H2);
  // layer-2 agg: out = elu(dis*agg + b2)
  k_agg<0><<<25000, 256, 0, stream>>>(H2, rowptr, dis, es, b2, d_out);
}